// Round 2
// baseline (180.959 us; speedup 1.0000x reference)
//
#include <hip/hip_runtime.h>

#define BB 32
#define CC 128
#define HH 128
#define WW 128
#define HWSZ (HH * WW)
#define CHW (CC * HWSZ)

// ---------------- Kernel 1: channel-wise mean+max reduce ----------------
// One thread = 4 consecutive w positions (float4). Loop over 128 channels.
__global__ __launch_bounds__(256) void sa_reduce_kernel(
    const float* __restrict__ x, float* __restrict__ ws) {
    int p4 = blockIdx.x * blockDim.x + threadIdx.x;   // 0 .. B*HW/4
    int pos = p4 * 4;
    int b = pos / HWSZ;
    int s = pos - b * HWSZ;

    const float4* xp = reinterpret_cast<const float4*>(x + (size_t)b * CHW + s);
    float4 v = xp[0];
    float4 sum = v;
    float4 mx = v;
    #pragma unroll 4
    for (int c = 1; c < CC; ++c) {
        float4 t = xp[c * (HWSZ / 4)];
        sum.x += t.x; sum.y += t.y; sum.z += t.z; sum.w += t.w;
        mx.x = fmaxf(mx.x, t.x);
        mx.y = fmaxf(mx.y, t.y);
        mx.z = fmaxf(mx.z, t.z);
        mx.w = fmaxf(mx.w, t.w);
    }
    const float inv = 1.0f / (float)CC;
    float4 avg = make_float4(sum.x * inv, sum.y * inv, sum.z * inv, sum.w * inv);

    // ws layout: [B][2][H][W]; ic=0 -> avg, ic=1 -> max (matches concat order)
    float4* wavg = reinterpret_cast<float4*>(ws + (size_t)(b * 2 + 0) * HWSZ + s);
    float4* wmax = reinterpret_cast<float4*>(ws + (size_t)(b * 2 + 1) * HWSZ + s);
    *wavg = avg;
    *wmax = mx;
}

// ---------------- Kernel 2: 7x7 conv + sigmoid + broadcast multiply ------
__global__ __launch_bounds__(256) void sa_apply_kernel(
    const float* __restrict__ x, const float* __restrict__ cw,
    const float* __restrict__ ws, float* __restrict__ out) {
    __shared__ float w_sh[2 * 49];
    int tid = threadIdx.x;
    if (tid < 98) w_sh[tid] = cw[tid];
    __syncthreads();

    int p4 = blockIdx.x * blockDim.x + tid;
    int pos = p4 * 4;
    int b = pos / HWSZ;
    int s = pos - b * HWSZ;
    int h = s / WW;
    int w0 = s - h * WW;

    float attn[4] = {0.f, 0.f, 0.f, 0.f};

    #pragma unroll
    for (int ic = 0; ic < 2; ++ic) {
        const float* m = ws + (size_t)(b * 2 + ic) * HWSZ;
        #pragma unroll
        for (int kh = 0; kh < 7; ++kh) {
            int hh = h + kh - 3;
            if (hh < 0 || hh >= HH) continue;
            const float* row = m + hh * WW;
            // 10-wide row segment covering w0-3 .. w0+6 (zero-padded)
            float seg[10];
            #pragma unroll
            for (int k = 0; k < 10; ++k) {
                int wwi = w0 - 3 + k;
                seg[k] = (wwi >= 0 && wwi < WW) ? row[wwi] : 0.0f;
            }
            #pragma unroll
            for (int kw = 0; kw < 7; ++kw) {
                float wgt = w_sh[ic * 49 + kh * 7 + kw];
                #pragma unroll
                for (int j = 0; j < 4; ++j)
                    attn[j] = fmaf(seg[kw + j], wgt, attn[j]);
            }
        }
    }

    float sig[4];
    #pragma unroll
    for (int j = 0; j < 4; ++j)
        sig[j] = 1.0f / (1.0f + __expf(-attn[j]));

    const float4* xp = reinterpret_cast<const float4*>(x + (size_t)b * CHW + s);
    float4*       op = reinterpret_cast<float4*>(out + (size_t)b * CHW + s);
    #pragma unroll 4
    for (int c = 0; c < CC; ++c) {
        float4 v = xp[c * (HWSZ / 4)];
        v.x *= sig[0];
        v.y *= sig[1];
        v.z *= sig[2];
        v.w *= sig[3];
        op[c * (HWSZ / 4)] = v;
    }
}

extern "C" void kernel_launch(void* const* d_in, const int* in_sizes, int n_in,
                              void* d_out, int out_size, void* d_ws, size_t ws_size,
                              hipStream_t stream) {
    const float* x  = (const float*)d_in[0];
    const float* cw = (const float*)d_in[1];
    float* out = (float*)d_out;
    float* ws  = (float*)d_ws;   // needs 2*B*H*W*4 = 4 MiB

    int total4 = BB * HWSZ / 4;          // 131072 threads
    int blocks = total4 / 256;           // 512 blocks
    sa_reduce_kernel<<<blocks, 256, 0, stream>>>(x, ws);
    sa_apply_kernel<<<blocks, 256, 0, stream>>>(x, cw, ws, out);
}

// Round 4
// 159.754 us; speedup vs baseline: 1.1327x; 1.1327x over previous
//
#include <hip/hip_runtime.h>

#define BB 32
#define CC 128
#define HH 128
#define WW 128
#define HWSZ (HH * WW)          // 16384
#define CHW (CC * HWSZ)         // 2097152
#define S4 (HWSZ / 4)           // 4096
#define P4TOT (BB * HWSZ / 4)   // 131072
#define NGRP 4
#define CPG (CC / NGRP)         // 32 channels per group
#define MAPS_OFF ((size_t)NGRP * BB * 2 * HWSZ)   // floats; partial region size

typedef float vfloat4 __attribute__((ext_vector_type(4)));

// ---------- K1: partial channel reduce (4-way channel split) ----------
// 2048 blocks x 256 thr; thread = 4 consecutive w, 32 channels.
__global__ __launch_bounds__(256) void k1_reduce_partial(
    const float* __restrict__ x, float* __restrict__ part) {
    int t = blockIdx.x * 256 + threadIdx.x;      // 0 .. 4*P4TOT-1
    int g = t >> 17;                              // t / P4TOT (0..3)
    int p4 = t & (P4TOT - 1);
    int pos = p4 * 4;
    int b = pos / HWSZ;
    int s = pos & (HWSZ - 1);

    const float4* xp = reinterpret_cast<const float4*>(
        x + (size_t)b * CHW + (size_t)(g * CPG) * HWSZ + s);
    float4 v = xp[0];
    float4 sum = v, mx = v;
    #pragma unroll 4
    for (int c = 1; c < CPG; ++c) {
        float4 tv = xp[c * (HWSZ / 4)];
        sum.x += tv.x; sum.y += tv.y; sum.z += tv.z; sum.w += tv.w;
        mx.x = fmaxf(mx.x, tv.x);
        mx.y = fmaxf(mx.y, tv.y);
        mx.z = fmaxf(mx.z, tv.z);
        mx.w = fmaxf(mx.w, tv.w);
    }
    // part layout: [g][b][2][HW]; i=0 raw sum, i=1 max
    float4* ps = reinterpret_cast<float4*>(part + (size_t)((g * BB + b) * 2 + 0) * HWSZ + s);
    float4* pm = reinterpret_cast<float4*>(part + (size_t)((g * BB + b) * 2 + 1) * HWSZ + s);
    *ps = sum;
    *pm = mx;
}

// ---------- K2: combine partials -> [B][2][HW] maps (avg, max) ----------
__global__ __launch_bounds__(256) void k2_combine(
    const float* __restrict__ part, float* __restrict__ maps) {
    int idx = blockIdx.x * 256 + threadIdx.x;     // 0 .. B*2*HW/4-1
    int m = idx * 4;
    int b = m / (2 * HWSZ);
    int r = m & (2 * HWSZ - 1);
    int i = r / HWSZ;
    int s = r & (HWSZ - 1);

    float4 acc = *reinterpret_cast<const float4*>(
        part + (size_t)((0 * BB + b) * 2 + i) * HWSZ + s);
    #pragma unroll
    for (int g = 1; g < NGRP; ++g) {
        float4 t = *reinterpret_cast<const float4*>(
            part + (size_t)((g * BB + b) * 2 + i) * HWSZ + s);
        if (i == 0) {
            acc.x += t.x; acc.y += t.y; acc.z += t.z; acc.w += t.w;
        } else {
            acc.x = fmaxf(acc.x, t.x);
            acc.y = fmaxf(acc.y, t.y);
            acc.z = fmaxf(acc.z, t.z);
            acc.w = fmaxf(acc.w, t.w);
        }
    }
    if (i == 0) {
        const float inv = 1.0f / (float)CC;
        acc.x *= inv; acc.y *= inv; acc.z *= inv; acc.w *= inv;
    }
    *reinterpret_cast<float4*>(maps + (size_t)(b * 2 + i) * HWSZ + s) = acc;
}

// ---------- K3: 7x7 conv + sigmoid -> sig [B][HW] ----------
__global__ __launch_bounds__(256) void k3_conv_sig(
    const float* __restrict__ maps, const float* __restrict__ cw,
    float* __restrict__ sig) {
    __shared__ float w_sh[2 * 49];
    int tid = threadIdx.x;
    if (tid < 98) w_sh[tid] = cw[tid];
    __syncthreads();

    int p4 = blockIdx.x * 256 + tid;
    int pos = p4 * 4;
    int b = pos / HWSZ;
    int s = pos & (HWSZ - 1);
    int h = s / WW;
    int w0 = s & (WW - 1);

    float attn[4] = {0.f, 0.f, 0.f, 0.f};
    #pragma unroll
    for (int ic = 0; ic < 2; ++ic) {
        const float* m = maps + (size_t)(b * 2 + ic) * HWSZ;
        #pragma unroll
        for (int kh = 0; kh < 7; ++kh) {
            int hh = h + kh - 3;
            if (hh < 0 || hh >= HH) continue;
            const float* row = m + hh * WW;
            float seg[10];
            #pragma unroll
            for (int k = 0; k < 10; ++k) {
                int wwi = w0 - 3 + k;
                seg[k] = (wwi >= 0 && wwi < WW) ? row[wwi] : 0.0f;
            }
            #pragma unroll
            for (int kw = 0; kw < 7; ++kw) {
                float wgt = w_sh[ic * 49 + kh * 7 + kw];
                #pragma unroll
                for (int j = 0; j < 4; ++j)
                    attn[j] = fmaf(seg[kw + j], wgt, attn[j]);
            }
        }
    }
    float4 sv;
    sv.x = 1.0f / (1.0f + __expf(-attn[0]));
    sv.y = 1.0f / (1.0f + __expf(-attn[1]));
    sv.z = 1.0f / (1.0f + __expf(-attn[2]));
    sv.w = 1.0f / (1.0f + __expf(-attn[3]));
    *reinterpret_cast<float4*>(sig + (size_t)b * HWSZ + s) = sv;
}

// ---------- K4: out = x * sig (broadcast over C), reversed stream ----------
__global__ __launch_bounds__(256) void k4_mul(
    const float* __restrict__ x, const float* __restrict__ sig,
    float* __restrict__ out) {
    const int TOT4 = BB * CC * HWSZ / 4;          // 16777216
    int stride = gridDim.x * blockDim.x;
    for (int j = blockIdx.x * blockDim.x + threadIdx.x; j < TOT4; j += stride) {
        int i = TOT4 - 1 - j;                     // reversed: maximize LLC hits on x
        int b = i >> 19;                          // / (CHW/4)
        int r = i & ((CHW / 4) - 1);
        int s4 = r & (S4 - 1);
        vfloat4 xv = reinterpret_cast<const vfloat4*>(x)[(size_t)i];
        vfloat4 sv = reinterpret_cast<const vfloat4*>(sig)[(size_t)b * S4 + s4];
        vfloat4 o = xv * sv;
        __builtin_nontemporal_store(o, reinterpret_cast<vfloat4*>(out) + (size_t)i);
    }
}

extern "C" void kernel_launch(void* const* d_in, const int* in_sizes, int n_in,
                              void* d_out, int out_size, void* d_ws, size_t ws_size,
                              hipStream_t stream) {
    const float* x  = (const float*)d_in[0];
    const float* cw = (const float*)d_in[1];
    float* out = (float*)d_out;
    float* ws  = (float*)d_ws;            // sig: 2 MiB

    // scratch inside d_out (fully overwritten by k4_mul):
    float* part = out;                    // [4][B][2][HW] = 16 MiB
    float* maps = out + MAPS_OFF;         // [B][2][HW]    =  4 MiB
    float* sig  = ws;                     // [B][HW]       =  2 MiB

    k1_reduce_partial<<<NGRP * P4TOT / 256, 256, 0, stream>>>(x, part);
    k2_combine<<<BB * 2 * HWSZ / 4 / 256, 256, 0, stream>>>(part, maps);
    k3_conv_sig<<<P4TOT / 256, 256, 0, stream>>>(maps, cw, sig);
    k4_mul<<<8192, 256, 0, stream>>>(x, sig, out);
}

// Round 5
// 141.259 us; speedup vs baseline: 1.2810x; 1.1309x over previous
//
#include <hip/hip_runtime.h>

#define BB 32
#define CC 128
#define HH 128
#define WW 128
#define HWSZ (HH * WW)          // 16384
#define CHW (CC * HWSZ)         // 2097152
#define S4 (HWSZ / 4)           // 4096
#define RPB 8                   // output rows per block
#define HALO 14                 // RPB + 6 (conv radius 3 each side)

typedef float vfloat4 __attribute__((ext_vector_type(4)));

__device__ __forceinline__ vfloat4 fmax4(vfloat4 a, vfloat4 b) {
    vfloat4 r;
    r.x = fmaxf(a.x, b.x);
    r.y = fmaxf(a.y, b.y);
    r.z = fmaxf(a.z, b.z);
    r.w = fmaxf(a.w, b.w);
    return r;
}

// One block = (batch b, 8-row band). Three phases, no global intermediates.
__global__ __launch_bounds__(256, 2) void sa_onepass(
    const float* __restrict__ x, const float* __restrict__ cw,
    float* __restrict__ out) {
    __shared__ float m_lds[2][HALO][WW];   // [avg/max][halo row][w] = 14 KiB
    __shared__ float wsh[2 * 49];

    const int tid = threadIdx.x;
    // XCD swizzle: adjacent h-bands of the same batch land on the same XCD
    // (round-robin dispatch: blockIdx % 8 = XCD), so halo reads hit L2.
    const int wg  = blockIdx.x;            // 0..511
    const int xcd = wg & 7;
    const int lin = wg >> 3;               // 0..63
    const int b   = xcd * 4 + (lin >> 4);  // 0..31
    const int hb  = lin & 15;              // 0..15
    const int h0  = hb * RPB;

    if (tid < 98) wsh[tid] = cw[tid];

    const int r0 = tid >> 5;               // 0..7  (halo row A; own row index)
    const int w4 = tid & 31;               // float4 column 0..31
    const float* xb = x + (size_t)b * CHW;

    // ---------- Phase 1: channel reduce rows h0-3 .. h0+10 ----------
    // Thread A-position: halo row r0; B-position: halo row r0+8 (waves 0-2 only).
    const bool actB = (r0 < HALO - 8);     // r0 < 6  -> wave-uniform
    const int gh_a = h0 - 3 + r0;
    const int gh_b = h0 - 3 + r0 + 8;
    const bool okA = (gh_a >= 0) && (gh_a < HH);
    const bool okB = actB && (gh_b < HH);  // gh_b >= 5 always
    const int cha = gh_a < 0 ? 0 : (gh_a > HH - 1 ? HH - 1 : gh_a);
    const int chb = gh_b > HH - 1 ? HH - 1 : gh_b;

    const vfloat4* pA = (const vfloat4*)(xb + cha * WW) + w4;
    const vfloat4* pB = (const vfloat4*)(xb + chb * WW) + w4;

    vfloat4 sumA, mxA;
    {
        vfloat4 v = pA[0];
        sumA = v; mxA = v;
    }
    #pragma unroll 4
    for (int c = 1; c < CC; ++c) {
        vfloat4 v = pA[(size_t)c * S4];
        sumA += v;
        mxA = fmax4(mxA, v);
    }
    vfloat4 sumB = {0.f, 0.f, 0.f, 0.f}, mxB = sumB;
    if (actB) {                             // whole wave 3 skips: no divergence
        vfloat4 v = pB[0];
        sumB = v; mxB = v;
        #pragma unroll 4
        for (int c = 1; c < CC; ++c) {
            vfloat4 t = pB[(size_t)c * S4];
            sumB += t;
            mxB = fmax4(mxB, t);
        }
    }

    const float invC = 1.0f / (float)CC;
    {
        vfloat4 avgA = sumA * invC;
        if (!okA) { avgA = (vfloat4){0,0,0,0}; mxA = (vfloat4){0,0,0,0}; }
        *(vfloat4*)&m_lds[0][r0][w4 * 4] = avgA;
        *(vfloat4*)&m_lds[1][r0][w4 * 4] = mxA;
        if (actB) {
            vfloat4 avgB = sumB * invC;
            if (!okB) { avgB = (vfloat4){0,0,0,0}; mxB = (vfloat4){0,0,0,0}; }
            *(vfloat4*)&m_lds[0][r0 + 8][w4 * 4] = avgB;
            *(vfloat4*)&m_lds[1][r0 + 8][w4 * 4] = mxB;
        }
    }
    __syncthreads();

    // ---------- Phase 2: 7x7 conv + sigmoid (all from LDS) ----------
    const int hr = r0;                      // own row within band
    const int w0 = w4 * 4;
    float attn[4] = {0.f, 0.f, 0.f, 0.f};
    #pragma unroll
    for (int ic = 0; ic < 2; ++ic) {
        #pragma unroll
        for (int kh = 0; kh < 7; ++kh) {
            // global input row = h0 + hr + kh - 3  <->  halo row hr + kh
            const float* row = &m_lds[ic][hr + kh][0];
            float seg[10];
            #pragma unroll
            for (int k = 0; k < 10; ++k) {
                int wi = w0 - 3 + k;
                seg[k] = (wi >= 0 && wi < WW) ? row[wi] : 0.0f;
            }
            #pragma unroll
            for (int kw = 0; kw < 7; ++kw) {
                float wgt = wsh[ic * 49 + kh * 7 + kw];
                attn[0] = fmaf(seg[kw + 0], wgt, attn[0]);
                attn[1] = fmaf(seg[kw + 1], wgt, attn[1]);
                attn[2] = fmaf(seg[kw + 2], wgt, attn[2]);
                attn[3] = fmaf(seg[kw + 3], wgt, attn[3]);
            }
        }
    }
    vfloat4 sig;
    sig.x = 1.0f / (1.0f + __expf(-attn[0]));
    sig.y = 1.0f / (1.0f + __expf(-attn[1]));
    sig.z = 1.0f / (1.0f + __expf(-attn[2]));
    sig.w = 1.0f / (1.0f + __expf(-attn[3]));

    // ---------- Phase 3: out = x * sig for own row, reversed c (LRU-friendly) --
    const int s = (h0 + hr) * WW + w0;
    const vfloat4* px = (const vfloat4*)xb + (s >> 2);
    vfloat4* po = (vfloat4*)(out + (size_t)b * CHW) + (s >> 2);
    #pragma unroll 4
    for (int c = CC - 1; c >= 0; --c) {
        vfloat4 v = px[(size_t)c * S4];
        v *= sig;
        __builtin_nontemporal_store(v, po + (size_t)c * S4);
    }
}

extern "C" void kernel_launch(void* const* d_in, const int* in_sizes, int n_in,
                              void* d_out, int out_size, void* d_ws, size_t ws_size,
                              hipStream_t stream) {
    const float* x  = (const float*)d_in[0];
    const float* cw = (const float*)d_in[1];
    float* out = (float*)d_out;

    sa_onepass<<<BB * (HH / RPB), 256, 0, stream>>>(x, cw, out);  // 512 blocks
}